// Round 4
// baseline (45440.491 us; speedup 1.0000x reference)
//
#include <hip/hip_runtime.h>
#include <stdint.h>

// ---------------------------------------------------------------------------
// Seq2seq LSTM autoencoder (T=4096, H=1024, L=2), fp32 end-to-end.
// Round 7: split readiness from data to kill LLC poll contention.
//   Round-6 post-mortem: per-step 2.89us with 0.48us VALU. 131k threads
//   spin-loading tagged data u64s = ~8 TB/s of polling traffic into the
//   Infinity Cache; congestion, not visibility latency, dominates.
//   New exchange protocol per step:
//     producer (lane 0 of wave 0): gathers the block's 8 h values via
//       __shfl, stores them as 4 relaxed agent u64s, then RELEASE-stores
//       a per-block flag (own 64B line). Single-thread stores => release
//       covers the data stores.
//     consumer: tid<128 poll own-layer flags (1 u32 line each), tid 128..255
//       poll instream flags; barrier; ALL threads then do exactly 2 u64
//       relaxed atomic data loads -> LDS; barrier; dot.
//   Poll traffic drops ~20x; streams are plain float (no tags, half bytes).
//   Data reads remain agent-scope atomics (bypass L2) => stale-L2 hazards
//   across XCDs / graph iterations remain impossible. Flags are fresh
//   arrays per phase (epoch separation), memset to 0 each launch.
// Geometry unchanged from round 6 (proven no-spill): 128 blocks x 512 thr
// per layer, 8 rows/block, weights in VGPRs, pair kernel = 256 blocks.
// Deadlock-free: layer-A blocks never wait on layer-B; flags monotone.
// ---------------------------------------------------------------------------

#define T_STEPS 4096
#define H_DIM   1024
#define NSLOT   4097
#define FLAG_STRIDE 16            // one u32 flag per 64B line
#define PANIC_ITERS (1u<<23)

using u32 = uint32_t;
using u64 = unsigned long long;

static __device__ __forceinline__ float sigf(float x){ return 1.0f/(1.0f+__expf(-x)); }
static __device__ __forceinline__ float tanh_f(float x){
  x = fminf(20.f, fmaxf(-20.f, x));
  float e = __expf(-2.f*x);
  return (1.f-e)/(1.f+e);
}

static __device__ __forceinline__ u64 pk2(float a, float b){
  return (u64)__float_as_uint(a) | (((u64)__float_as_uint(b))<<32);
}
// one u64 agent atomic load -> two fp32 into LDS
static __device__ __forceinline__ void ld2a(const float* p, float* dst){
  u64 v=__hip_atomic_load((const u64*)p,__ATOMIC_RELAXED,__HIP_MEMORY_SCOPE_AGENT);
  dst[0]=__uint_as_float((u32)v);
  dst[1]=__uint_as_float((u32)(v>>32));
}
static __device__ __forceinline__ float ld1a(const float* p){
  u32 v=__hip_atomic_load((const u32*)p,__ATOMIC_RELAXED,__HIP_MEMORY_SCOPE_AGENT);
  return __uint_as_float(v);
}

// Spin until *f >= want. Dependent-load self-pacing (~350ns cadence);
// panic escape for true deadlocks only.
static __device__ __forceinline__ void poll_flag(const u32* __restrict__ f,
                                                 u32 want, u32* panic){
  u32 it=0;
  while(__hip_atomic_load(f,__ATOMIC_RELAXED,__HIP_MEMORY_SCOPE_AGENT) < want){
    if(((++it)&255u)==0u){
      if(__hip_atomic_load(panic,__ATOMIC_RELAXED,__HIP_MEMORY_SCOPE_AGENT)==0xDEADBEEFu) break;
      if(it>PANIC_ITERS){ __hip_atomic_store(panic,0xDEADBEEFu,__ATOMIC_RELAXED,__HIP_MEMORY_SCOPE_AGENT); break; }
      __builtin_amdgcn_s_sleep(1);
    }
  }
}

// One LSTM layer over T steps. kb = block index within the layer (0..127).
// Block owns h-rows hr0..hr0+7. 8 waves: wave w -> gate g=w>>1, quad q=w&1;
// lane l = one 32-col segment of the concatenated K=2048 [W_ih|W_hh] dot.
// Streams are plain float slots [NSLOT][1024]; readiness via per-producer
// flags: flag[kb] = number of slots this block has published.
// mode 0: input = raw x.  mode 1/3: input = flagged stream.
// mode 2: input = CONSTANT slot (staged once at entry; cross-kernel data).
static __device__ __forceinline__ void lstm_scan_body(
    int kb, int tid, float* st, float* gl,
    const float* __restrict__ xin,
    const float* __restrict__ instream,
    float*       __restrict__ own,
    const u32*  __restrict__ flagIn,   // producer flags of input stream
    u32*        __restrict__ flagOwn,  // this layer's flags
    const float* __restrict__ Wih, const float* __restrict__ Whh,
    const float* __restrict__ bih, const float* __restrict__ bhh,
    const float* __restrict__ c0,      // null -> zeros
    float*       __restrict__ cout,    // final c per row
    const float* __restrict__ h0slot,  // plain h0 slot; null -> zeros
    float*       __restrict__ fh_out,  // if non-null: write final h (enc L1)
    u32* __restrict__ panic,
    int mode)
{
  const int hr0=kb*8;
  const int w=tid>>6, l=tid&63;
  const int g=w>>1, q=w&1;
  const int grow0=(g<<10)+hr0+(q<<2);      // first of 4 owned gate rows
  const int e0 = 2*tid;                    // first owned stream element
  const int fb  = e0 + 4*(e0>>5);          // stage word, IN part (2 elems)
  const int fbH = 1152+fb;                 // stage word, H part
  const int sb  = l*36;                    // dot segment word base
  u32* myflag = flagOwn + kb*FLAG_STRIDE;
  const bool has_in = (mode==1)||(mode==3);

  // fp32 weights in registers: 4 gate rows x 32-col segment
  float wr0[32],wr1[32],wr2[32],wr3[32];
  {
    const float* srcb = (l<32) ? Wih + (size_t)grow0*H_DIM + l*32
                               : Whh + (size_t)grow0*H_DIM + (l-32)*32;
    #pragma unroll
    for(int i=0;i<8;i++){
      float4 a0=*(const float4*)(srcb + i*4);
      float4 a1=*(const float4*)(srcb + 1024 + i*4);
      float4 a2=*(const float4*)(srcb + 2048 + i*4);
      float4 a3=*(const float4*)(srcb + 3072 + i*4);
      wr0[4*i]=a0.x; wr0[4*i+1]=a0.y; wr0[4*i+2]=a0.z; wr0[4*i+3]=a0.w;
      wr1[4*i]=a1.x; wr1[4*i+1]=a1.y; wr1[4*i+2]=a1.z; wr1[4*i+3]=a1.w;
      wr2[4*i]=a2.x; wr2[4*i+1]=a2.y; wr2[4*i+2]=a2.z; wr2[4*i+3]=a2.w;
      wr3[4*i]=a3.x; wr3[4*i+1]=a3.y; wr3[4*i+2]=a3.z; wr3[4*i+3]=a3.w;
    }
  }

  float bI=0,bF=0,bG=0,bO=0,c_st=0.f,h_st=0.f;   // gate state valid tid<8
  if(tid<8){
    int o=hr0+tid;
    bI=bih[o]       + bhh[o];
    bF=bih[o+1024]  + bhh[o+1024];
    bG=bih[o+2048]  + bhh[o+2048];
    bO=bih[o+3072]  + bhh[o+3072];
    if(c0)     c_st=c0[o];
    if(h0slot) h_st=ld1a(h0slot+o);
  }
  // publish slot 0 (h0): lane 0 of wave 0 stores all 8 + release flag = 1
  if(w==0){
    float h0v=__shfl(h_st,0,64), h1v=__shfl(h_st,1,64);
    float h2v=__shfl(h_st,2,64), h3v=__shfl(h_st,3,64);
    float h4v=__shfl(h_st,4,64), h5v=__shfl(h_st,5,64);
    float h6v=__shfl(h_st,6,64), h7v=__shfl(h_st,7,64);
    if(l==0){
      u64* dst=(u64*)(own + hr0);
      __hip_atomic_store(dst+0, pk2(h0v,h1v), __ATOMIC_RELAXED,__HIP_MEMORY_SCOPE_AGENT);
      __hip_atomic_store(dst+1, pk2(h2v,h3v), __ATOMIC_RELAXED,__HIP_MEMORY_SCOPE_AGENT);
      __hip_atomic_store(dst+2, pk2(h4v,h5v), __ATOMIC_RELAXED,__HIP_MEMORY_SCOPE_AGENT);
      __hip_atomic_store(dst+3, pk2(h6v,h7v), __ATOMIC_RELAXED,__HIP_MEMORY_SCOPE_AGENT);
      __hip_atomic_store(myflag, 1u, __ATOMIC_RELEASE,__HIP_MEMORY_SCOPE_AGENT);
    }
  }
  if(mode==2){                     // constant input: cross-kernel data, no flag
    ld2a(instream+e0, st+fb);
  }

  for(int t=0;t<T_STEPS;++t){
    // --- A: readiness polls (1 flag line per polling thread) ---
    if(tid<128){
      poll_flag(flagOwn + tid*FLAG_STRIDE, (u32)(t+1), panic);
    } else if(has_in && tid<256){
      poll_flag(flagIn + (tid-128)*FLAG_STRIDE, (u32)(t+2), panic);
    }
    __syncthreads();
    // --- C: data loads -> LDS (one burst, 2 u64 atomics/thread) ---
    if(mode==0){
      float2 xv=*(const float2*)(xin + (size_t)t*H_DIM + e0);
      st[fb]=xv.x; st[fb+1]=xv.y;
    } else if(has_in){
      ld2a(instream + (size_t)(t+1)*H_DIM + e0, st+fb);
    }
    ld2a(own + (size_t)t*H_DIM + e0, st+fbH);
    __syncthreads();
    // --- D: dot + reduce ---
    float p0=0.f,p1=0.f,p2=0.f,p3=0.f;
    #pragma unroll
    for(int i=0;i<8;i++){
      float4 s=*(const float4*)(st+sb+i*4);
      p0+=s.x*wr0[4*i]+s.y*wr0[4*i+1]+s.z*wr0[4*i+2]+s.w*wr0[4*i+3];
      p1+=s.x*wr1[4*i]+s.y*wr1[4*i+1]+s.z*wr1[4*i+2]+s.w*wr1[4*i+3];
      p2+=s.x*wr2[4*i]+s.y*wr2[4*i+1]+s.z*wr2[4*i+2]+s.w*wr2[4*i+3];
      p3+=s.x*wr3[4*i]+s.y*wr3[4*i+1]+s.z*wr3[4*i+2]+s.w*wr3[4*i+3];
    }
    #pragma unroll
    for(int off=32;off;off>>=1){
      p0+=__shfl_down(p0,off,64); p1+=__shfl_down(p1,off,64);
      p2+=__shfl_down(p2,off,64); p3+=__shfl_down(p3,off,64);
    }
    if(l==0){ gl[w*4+0]=p0; gl[w*4+1]=p1; gl[w*4+2]=p2; gl[w*4+3]=p3; }
    __syncthreads();
    // --- E: gates + publish slot t+1 ---
    if(tid<8){
      // gl[g*8 + r]: gate g partial for block h-row r (r = tid)
      float gi=bI+gl[tid], gf=bF+gl[8+tid], gg=bG+gl[16+tid], go=bO+gl[24+tid];
      c_st = sigf(gf)*c_st + sigf(gi)*tanh_f(gg);
      h_st = sigf(go)*tanh_f(c_st);
      if(t==T_STEPS-1){
        cout[hr0+tid]=c_st;
        if(fh_out) fh_out[hr0+tid]=h_st;
      }
    }
    if(w==0){
      float h0v=__shfl(h_st,0,64), h1v=__shfl(h_st,1,64);
      float h2v=__shfl(h_st,2,64), h3v=__shfl(h_st,3,64);
      float h4v=__shfl(h_st,4,64), h5v=__shfl(h_st,5,64);
      float h6v=__shfl(h_st,6,64), h7v=__shfl(h_st,7,64);
      if(l==0){
        u64* dst=(u64*)(own + (size_t)(t+1)*H_DIM + hr0);
        __hip_atomic_store(dst+0, pk2(h0v,h1v), __ATOMIC_RELAXED,__HIP_MEMORY_SCOPE_AGENT);
        __hip_atomic_store(dst+1, pk2(h2v,h3v), __ATOMIC_RELAXED,__HIP_MEMORY_SCOPE_AGENT);
        __hip_atomic_store(dst+2, pk2(h4v,h5v), __ATOMIC_RELAXED,__HIP_MEMORY_SCOPE_AGENT);
        __hip_atomic_store(dst+3, pk2(h6v,h7v), __ATOMIC_RELAXED,__HIP_MEMORY_SCOPE_AGENT);
        __hip_atomic_store(myflag, (u32)(t+2), __ATOMIC_RELEASE,__HIP_MEMORY_SCOPE_AGENT);
      }
    }
    // no trailing barrier: gl reads above complete before the next C-phase
    // barrier, which precedes the next gl writes.
  }
}

// Fused layer pair: blocks [0,128) = layer A, [128,256) = layer B.
// B consumes A's stream with 1-step skew. A never waits on B.
__global__ __launch_bounds__(512,2) void lstm_scan_pair(
    const float* __restrict__ xinA,
    const float* __restrict__ insA, float* __restrict__ ownA,
    const u32* __restrict__ fInA, u32* __restrict__ fOwnA,
    const float* __restrict__ WihA, const float* __restrict__ WhhA,
    const float* __restrict__ bihA, const float* __restrict__ bhhA,
    const float* __restrict__ c0A, float* __restrict__ coutA,
    const float* __restrict__ h0A, float* __restrict__ fhA, int modeA,
    const float* __restrict__ insB, float* __restrict__ ownB,
    const u32* __restrict__ fInB, u32* __restrict__ fOwnB,
    const float* __restrict__ WihB, const float* __restrict__ WhhB,
    const float* __restrict__ bihB, const float* __restrict__ bhhB,
    const float* __restrict__ c0B, float* __restrict__ coutB,
    const float* __restrict__ h0B, float* __restrict__ fhB, int modeB,
    u32* __restrict__ panic)
{
  __shared__ __align__(16) float st[2304];
  __shared__ float gl[32];
  const int b=blockIdx.x, tid=threadIdx.x;
  if(b<128){
    lstm_scan_body(b, tid, st, gl, xinA, insA, ownA, fInA, fOwnA,
                   WihA, WhhA, bihA, bhhA, c0A, coutA, h0A, fhA, panic, modeA);
  } else {
    lstm_scan_body(b-128, tid, st, gl, nullptr, insB, ownB, fInB, fOwnB,
                   WihB, WhhB, bihB, bhhB, c0B, coutB, h0B, fhB, panic, modeB);
  }
}

// out[(4095-tp), o] = leaky( sum_k oW[o,k] * h1d[tp][k] + ob[o] )
__global__ __launch_bounds__(256) void proj_out(
    const float* __restrict__ SB, const float* __restrict__ oW,
    const float* __restrict__ ob, float* __restrict__ out)
{
  __shared__ __align__(16) float hb[1024];
  const int tp=blockIdx.x, tid=threadIdx.x;
  ld2a(SB + (size_t)(tp+1)*H_DIM + tid*4,     hb + tid*4);
  ld2a(SB + (size_t)(tp+1)*H_DIM + tid*4 + 2, hb + tid*4 + 2);
  __syncthreads();
  #pragma unroll
  for(int j=0;j<4;j++){
    int o = tid + 256*j;
    const float* wr = oW + (size_t)o*H_DIM;
    float acc=0.f;
    for(int k=0;k<1024;k+=4){
      float4 wv=*(const float4*)(wr+k);
      acc += wv.x*hb[k]+wv.y*hb[k+1]+wv.z*hb[k+2]+wv.w*hb[k+3];
    }
    acc += ob[o];
    acc = acc>0.f ? acc : 0.01f*acc;
    out[(size_t)(4095-tp)*H_DIM + o]=acc;
  }
}

extern "C" void kernel_launch(void* const* d_in, const int* in_sizes, int n_in,
                              void* d_out, int out_size, void* d_ws, size_t ws_size,
                              hipStream_t stream) {
  const float* x    = (const float*)d_in[0];
  const float* eWih = (const float*)d_in[1];
  const float* eWhh = (const float*)d_in[2];
  const float* ebih = (const float*)d_in[3];
  const float* ebhh = (const float*)d_in[4];
  const float* dWih = (const float*)d_in[5];
  const float* dWhh = (const float*)d_in[6];
  const float* dbih = (const float*)d_in[7];
  const float* dbhh = (const float*)d_in[8];
  const float* oW   = (const float*)d_in[9];
  const float* ob   = (const float*)d_in[10];
  float* out = (float*)d_out;
  u32* ws = (u32*)d_ws;

  const size_t REGION = (size_t)NSLOT*H_DIM;       // dwords per stream
  float* SA    = (float*)ws;
  float* SB    = (float*)(ws + REGION);
  float* CA    = (float*)(ws + 2*REGION);          // 2048 floats: enc c finals
  u32*   panic = ws + 2*REGION + 2048;
  u32*   F1A   = panic + 64;                       // 128 flags x 16 dw each
  u32*   F1B   = F1A + 128*FLAG_STRIDE;
  u32*   F2A   = F1B + 128*FLAG_STRIDE;
  u32*   F2B   = F2A + 128*FLAG_STRIDE;
  const size_t LSTRIDE = (size_t)4096*1024;        // per-layer weight stride

  // clear CA + panic + all flag sets (streams need no clear: flag-gated)
  size_t clr_bytes = (2048 + 64 + 4*128*FLAG_STRIDE)*4;
  hipMemsetAsync((void*)(ws + 2*REGION), 0, clr_bytes, stream);

  // Phase 1: enc L0 (mode 0, x -> SA, flags F1A, zero init) || enc L1
  // (mode 1, SA/F1A -> SB/F1B, zero init, writes final_hidden to out tail).
  lstm_scan_pair<<<256,512,0,stream>>>(
      x, nullptr, SA, nullptr, F1A,
      eWih, eWhh, ebih, ebhh,
      nullptr, CA, nullptr, nullptr, 0,
      SA, SB, F1A, F1B,
      eWih+LSTRIDE, eWhh+LSTRIDE, ebih+4096, ebhh+4096,
      nullptr, CA+1024, nullptr, out + (size_t)T_STEPS*H_DIM, 1,
      panic);

  // Phase 2: dec L0 (mode 2, const input = final_hidden = SB slot 4096,
  // stream SA reused with flags F2A, init h=SA slot 4096 / c=CA) || dec L1
  // (mode 3, SA/F2A -> SB/F2B, init h=SB slot 4096 / c=CA+1024).
  lstm_scan_pair<<<256,512,0,stream>>>(
      nullptr, SB + (size_t)4096*H_DIM, SA, nullptr, F2A,
      dWih, dWhh, dbih, dbhh,
      CA, CA, SA + (size_t)4096*H_DIM, nullptr, 2,
      SA, SB, F2A, F2B,
      dWih+LSTRIDE, dWhh+LSTRIDE, dbih+4096, dbhh+4096,
      CA+1024, CA+1024, SB + (size_t)4096*H_DIM, nullptr, 3,
      panic);

  // projection + leaky ReLU + flip
  proj_out<<<4096,256,0,stream>>>(SB, oW, ob, out);
}

// Round 5
// 38617.090 us; speedup vs baseline: 1.1767x; 1.1767x over previous
//
#include <hip/hip_runtime.h>
#include <stdint.h>

// ---------------------------------------------------------------------------
// Seq2seq LSTM autoencoder (T=4096, H=1024, L=2), fp32 end-to-end.
// Round 8: revert to round-6 tagged single-hop exchange (round 7's flag
// split added a 2nd LLC round trip -> 2x regression), then cut the
// block-internal epilogue off the critical path:
//   - wave-per-row: wave w owns h-row r (all 4 gates); lane l = one 32-col
//     segment of the concatenated K=2048 [W_ih|W_hh] dot. Gate reduce is
//     in-wave (shfl); lane 0 computes c,h and publishes its row directly.
//     No cross-wave gl[] exchange, no tid<8 serialization.
//   - LDS double-buffered staging -> ONE __syncthreads per step (fill
//     buf[t&1] -> barrier -> dot; intra-block skew <=1 so buffers never
//     collide: a wave can only reach buffer reuse after the next barrier).
//   - sleep-free poll (panic + s_sleep(1) every 256 iters only): poll
//     period ~= one LLC load RT; round 7 proved contention is not the
//     limiter, so pacing sleep only added discovery latency.
//   - proj_out re-tiled: 256 blocks x 16 timesteps, h staged in LDS,
//     out_W traffic 16 GB -> 1 GB (was ~1.3 ms, now ~0.2 ms).
// Exchange protocol (round-6 proven): tagged u64 per element
// ((MAGIC<<16|lo16),(MAGIC<<16|hi16)), agent-scope relaxed atomics, data
// IS the readiness signal (single LLC hop). Streams u64[NSLOT][1024].
// Geometry: 128 blocks x 512 thr per layer (8 rows/block), pair = 256
// blocks -> 1 block/CU (launch_bounds(512,2) => 2 waves/SIMD, 256 VGPR).
// Schedule: pair(enc L0, enc L1) -> pair(dec L0, dec L1) -> proj.
// Deadlock-free: layer-A never waits on layer-B; intra-block wave deps are
// publish-before-poll within the same barrier epoch.
// ---------------------------------------------------------------------------

#define T_STEPS 4096
#define H_DIM   1024
#define SLOT_U64 1024             // 1024 elements x (2 tagged dwords = 1 u64)
#define SLOT_DW  2048
#define NSLOT   4097
#define M1 0x7E57u
#define M2 0x7E58u
#define PANIC_ITERS (1u<<23)

using u32 = uint32_t;
using u64 = unsigned long long;

static __device__ __forceinline__ float sigf(float x){ return 1.0f/(1.0f+__expf(-x)); }
static __device__ __forceinline__ float tanh_f(float x){
  x = fminf(20.f, fmaxf(-20.f, x));
  float e = __expf(-2.f*x);
  return (1.f-e)/(1.f+e);
}

static __device__ __forceinline__ bool tag_ok(u64 v, u32 magic){
  return ((((u32)(v>>16))&0xFFFFu)==magic) & (((u32)(v>>48))==magic);
}
static __device__ __forceinline__ float untag1(u64 v){
  return __uint_as_float( (((u32)v)&0xFFFFu) | (((u32)(v>>32))<<16) );
}
static __device__ __forceinline__ u64 tag1(u32 magic, float h){
  u32 b=__float_as_uint(h);
  u64 lo = (u64)((magic<<16)|(b&0xFFFFu));
  u64 hi = ((u64)((magic<<16)|(b>>16)))<<32;
  return hi|lo;
}

// Poll 2 tagged elements until valid; deposit into LDS. Sleep-free spin:
// the dependent LLC load (~700ns) self-paces; panic escape every 256 iters.
static __device__ __forceinline__ void poll_h2(const u64* __restrict__ q,
                                               u32 magic, float* dst,
                                               u32* panic){
  u64 v0=0,v1=0; bool ok0=false,ok1=false; u32 it=0;
  for(;;){
    if(!ok0) v0=__hip_atomic_load(q,  __ATOMIC_RELAXED,__HIP_MEMORY_SCOPE_AGENT);
    if(!ok1) v1=__hip_atomic_load(q+1,__ATOMIC_RELAXED,__HIP_MEMORY_SCOPE_AGENT);
    ok0 = ok0 || tag_ok(v0,magic);
    ok1 = ok1 || tag_ok(v1,magic);
    if(ok0 & ok1) break;
    if(((++it)&255u)==0u){
      if(__hip_atomic_load(panic,__ATOMIC_RELAXED,__HIP_MEMORY_SCOPE_AGENT)==0xDEADBEEFu) break;
      if(it>PANIC_ITERS){ __hip_atomic_store(panic,0xDEADBEEFu,__ATOMIC_RELAXED,__HIP_MEMORY_SCOPE_AGENT); break; }
      __builtin_amdgcn_s_sleep(1);
    }
  }
  dst[0]=untag1(v0);
  dst[1]=untag1(v1);
}

// Poll 2 IN + 2 H tagged elements concurrently (modes 1/3).
static __device__ __forceinline__ void poll_in2h2(const u64* __restrict__ qa, u32 mA,
                                                  const u64* __restrict__ qb, u32 mB,
                                                  float* da, float* db, u32* panic){
  u64 a0=0,a1=0,b0=0,b1=0; bool oa0=false,oa1=false,ob0=false,ob1=false; u32 it=0;
  for(;;){
    if(!oa0) a0=__hip_atomic_load(qa,  __ATOMIC_RELAXED,__HIP_MEMORY_SCOPE_AGENT);
    if(!oa1) a1=__hip_atomic_load(qa+1,__ATOMIC_RELAXED,__HIP_MEMORY_SCOPE_AGENT);
    if(!ob0) b0=__hip_atomic_load(qb,  __ATOMIC_RELAXED,__HIP_MEMORY_SCOPE_AGENT);
    if(!ob1) b1=__hip_atomic_load(qb+1,__ATOMIC_RELAXED,__HIP_MEMORY_SCOPE_AGENT);
    oa0 = oa0 || tag_ok(a0,mA);
    oa1 = oa1 || tag_ok(a1,mA);
    ob0 = ob0 || tag_ok(b0,mB);
    ob1 = ob1 || tag_ok(b1,mB);
    if(oa0 & oa1 & ob0 & ob1) break;
    if(((++it)&255u)==0u){
      if(__hip_atomic_load(panic,__ATOMIC_RELAXED,__HIP_MEMORY_SCOPE_AGENT)==0xDEADBEEFu) break;
      if(it>PANIC_ITERS){ __hip_atomic_store(panic,0xDEADBEEFu,__ATOMIC_RELAXED,__HIP_MEMORY_SCOPE_AGENT); break; }
      __builtin_amdgcn_s_sleep(1);
    }
  }
  da[0]=untag1(a0); da[1]=untag1(a1);
  db[0]=untag1(b0); db[1]=untag1(b1);
}

// One LSTM layer over T steps. kb = block index within the layer (0..127).
// Block owns h-rows hr0..hr0+7; wave w owns row r=hr0+w entirely (4 gates).
// Lane l = one 32-col segment (lanes 0-31 input part, 32-63 h part).
// Thread stages stream elements 2*tid, 2*tid+1 of both IN and H parts.
// mode 0: input = raw x.  mode 1/3: input = tagged stream (m_in).
// mode 2: input = CONSTANT tagged slot (staged once into both buffers).
static __device__ __forceinline__ void lstm_scan_body(
    int kb, int tid, float (*st)[2304],
    const float* __restrict__ xin,
    const u64*  __restrict__ instream,
    u64*        __restrict__ own,
    u32 m_in, u32 m_own,
    const float* __restrict__ Wih, const float* __restrict__ Whh,
    const float* __restrict__ bih, const float* __restrict__ bhh,
    const float* __restrict__ c0,      // null -> zeros
    float*       __restrict__ cout,    // final c per row
    const u64*  __restrict__ h0slot,   // tagged slot holding h0; null -> zeros
    float*       __restrict__ fh_out,  // if non-null: write final h (enc L1)
    u32* __restrict__ panic,
    int mode)
{
  const int hr0=kb*8;
  const int w=tid>>6, l=tid&63;
  const int r = hr0 + w;                   // this wave's h row
  const int e0 = 2*tid;                    // first owned stream element
  const int fb  = e0 + 4*(e0>>5);          // stage word, IN part (2 elems)
  const int fbH = 1152+fb;                 // stage word, H part
  const int sb  = l*36;                    // dot segment word base

  // fp32 weights in registers: 4 gate rows (i,f,g,o) x 32-col segment.
  // Same per-lane segment and MAC chain order as round 6 -> bit-identical.
  float wr0[32],wr1[32],wr2[32],wr3[32];
  {
    const size_t GS = (size_t)1024*1024;   // gate stride in floats (1024 rows)
    const float* srcb = (l<32) ? Wih + (size_t)r*H_DIM + l*32
                               : Whh + (size_t)r*H_DIM + (l-32)*32;
    #pragma unroll
    for(int i=0;i<8;i++){
      float4 a0=*(const float4*)(srcb + i*4);
      float4 a1=*(const float4*)(srcb + GS + i*4);
      float4 a2=*(const float4*)(srcb + 2*GS + i*4);
      float4 a3=*(const float4*)(srcb + 3*GS + i*4);
      wr0[4*i]=a0.x; wr0[4*i+1]=a0.y; wr0[4*i+2]=a0.z; wr0[4*i+3]=a0.w;
      wr1[4*i]=a1.x; wr1[4*i+1]=a1.y; wr1[4*i+2]=a1.z; wr1[4*i+3]=a1.w;
      wr2[4*i]=a2.x; wr2[4*i+1]=a2.y; wr2[4*i+2]=a2.z; wr2[4*i+3]=a2.w;
      wr3[4*i]=a3.x; wr3[4*i+1]=a3.y; wr3[4*i+2]=a3.z; wr3[4*i+3]=a3.w;
    }
  }

  float bI=0,bF=0,bG=0,bO=0,c_st=0.f,h_st=0.f;   // valid on lane 0 of each wave
  if(l==0){
    bI=bih[r]       + bhh[r];
    bF=bih[r+1024]  + bhh[r+1024];
    bG=bih[r+2048]  + bhh[r+2048];
    bO=bih[r+3072]  + bhh[r+3072];
    if(c0)     c_st=c0[r];
    if(h0slot) h_st=untag1(h0slot[r]);
    // publish slot 0 (h0) for this wave's row
    __hip_atomic_store(own + r, tag1(m_own,h_st), __ATOMIC_RELAXED,__HIP_MEMORY_SCOPE_AGENT);
  }
  if(mode==2){                 // constant input: stage once into BOTH buffers
    float v0=untag1(instream[e0]), v1=untag1(instream[e0+1]);
    st[0][fb]=v0; st[0][fb+1]=v1;
    st[1][fb]=v0; st[1][fb+1]=v1;
  }

  for(int t=0;t<T_STEPS;++t){
    float* S = st[t&1];
    // --- fill buf[t&1] (poll = single-hop tagged exchange) ---
    if(mode==0){
      float2 xv=*(const float2*)(xin + (size_t)t*H_DIM + e0);  // issue early
      poll_h2(own + (size_t)t*SLOT_U64 + e0, m_own, S+fbH, panic);
      S[fb]=xv.x; S[fb+1]=xv.y;                                // lands during poll
    } else if(mode==2){
      poll_h2(own + (size_t)t*SLOT_U64 + e0, m_own, S+fbH, panic);
    } else {
      poll_in2h2(instream + (size_t)(t+1)*SLOT_U64 + e0, m_in,
                 own      + (size_t)t*SLOT_U64     + e0, m_own,
                 S+fb, S+fbH, panic);
    }
    __syncthreads();                 // ONE barrier per step
    // --- dot: 4 gates of row r over this lane's 32-col segment ---
    float p0=0.f,p1=0.f,p2=0.f,p3=0.f;
    #pragma unroll
    for(int i=0;i<8;i++){
      float4 s=*(const float4*)(S+sb+i*4);
      p0+=s.x*wr0[4*i]+s.y*wr0[4*i+1]+s.z*wr0[4*i+2]+s.w*wr0[4*i+3];
      p1+=s.x*wr1[4*i]+s.y*wr1[4*i+1]+s.z*wr1[4*i+2]+s.w*wr1[4*i+3];
      p2+=s.x*wr2[4*i]+s.y*wr2[4*i+1]+s.z*wr2[4*i+2]+s.w*wr2[4*i+3];
      p3+=s.x*wr3[4*i]+s.y*wr3[4*i+1]+s.z*wr3[4*i+2]+s.w*wr3[4*i+3];
    }
    #pragma unroll
    for(int off=32;off;off>>=1){
      p0+=__shfl_down(p0,off,64); p1+=__shfl_down(p1,off,64);
      p2+=__shfl_down(p2,off,64); p3+=__shfl_down(p3,off,64);
    }
    // --- gates + publish, fully in-wave (lane 0) ---
    if(l==0){
      float gi=bI+p0, gf=bF+p1, gg=bG+p2, go=bO+p3;
      c_st = sigf(gf)*c_st + sigf(gi)*tanh_f(gg);
      h_st = sigf(go)*tanh_f(c_st);
      __hip_atomic_store(own + (size_t)(t+1)*SLOT_U64 + r,
                         tag1(m_own,h_st), __ATOMIC_RELAXED,__HIP_MEMORY_SCOPE_AGENT);
      if(t==T_STEPS-1){
        cout[r]=c_st;
        if(fh_out) fh_out[r]=h_st;
      }
    }
    // no 2nd barrier: next iteration fills the OTHER buffer; a wave can
    // only reach THIS buffer again after all waves pass the next barrier.
  }
}

// Fused layer pair: blocks [0,128) = layer A, [128,256) = layer B.
// B consumes A's stream with 1-step skew. A never waits on B.
__global__ __launch_bounds__(512,2) void lstm_scan_pair(
    const float* __restrict__ xinA,
    const u64*  __restrict__ insA, u64* __restrict__ ownA, u32 miA, u32 moA,
    const float* __restrict__ WihA, const float* __restrict__ WhhA,
    const float* __restrict__ bihA, const float* __restrict__ bhhA,
    const float* __restrict__ c0A, float* __restrict__ coutA,
    const u64*  __restrict__ h0A, float* __restrict__ fhA, int modeA,
    const u64*  __restrict__ insB, u64* __restrict__ ownB, u32 miB, u32 moB,
    const float* __restrict__ WihB, const float* __restrict__ WhhB,
    const float* __restrict__ bihB, const float* __restrict__ bhhB,
    const float* __restrict__ c0B, float* __restrict__ coutB,
    const u64*  __restrict__ h0B, float* __restrict__ fhB, int modeB,
    u32* __restrict__ panic)
{
  __shared__ __align__(16) float st[2][2304];
  const int b=blockIdx.x, tid=threadIdx.x;
  if(b<128){
    lstm_scan_body(b, tid, st, xinA, insA, ownA, miA, moA,
                   WihA, WhhA, bihA, bhhA, c0A, coutA, h0A, fhA, panic, modeA);
  } else {
    lstm_scan_body(b-128, tid, st, nullptr, insB, ownB, miB, moB,
                   WihB, WhhB, bihB, bhhB, c0B, coutB, h0B, fhB, panic, modeB);
  }
}

// out[(4095-tp), o] = leaky( sum_k oW[o,k] * h1d[tp][k] + ob[o] )
// Tiled: each block handles PTILE timesteps, staging h in LDS, so out_W is
// read 256x total (1 GB LLC traffic) instead of 4096x (16 GB).
#define PTILE 16
__global__ __launch_bounds__(256,2) void proj_out(
    const u64* __restrict__ SB, const float* __restrict__ oW,
    const float* __restrict__ ob, float* __restrict__ out)
{
  __shared__ __align__(16) float hb[PTILE][1024];
  const int tp0=blockIdx.x*PTILE, tid=threadIdx.x;
  for(int i=0;i<PTILE;i++){
    u64 v0=SB[(size_t)(tp0+i+1)*SLOT_U64 + tid*4 + 0];
    u64 v1=SB[(size_t)(tp0+i+1)*SLOT_U64 + tid*4 + 1];
    u64 v2=SB[(size_t)(tp0+i+1)*SLOT_U64 + tid*4 + 2];
    u64 v3=SB[(size_t)(tp0+i+1)*SLOT_U64 + tid*4 + 3];
    float4 f; f.x=untag1(v0); f.y=untag1(v1); f.z=untag1(v2); f.w=untag1(v3);
    *(float4*)&hb[i][tid*4]=f;
  }
  __syncthreads();
  #pragma unroll
  for(int j=0;j<4;j++){
    int o = tid + 256*j;
    const float* wr = oW + (size_t)o*H_DIM;
    float acc[PTILE];
    #pragma unroll
    for(int i=0;i<PTILE;i++) acc[i]=0.f;
    for(int k=0;k<1024;k+=4){
      float4 wv=*(const float4*)(wr+k);
      #pragma unroll
      for(int i=0;i<PTILE;i++){
        acc[i] += wv.x*hb[i][k]+wv.y*hb[i][k+1]+wv.z*hb[i][k+2]+wv.w*hb[i][k+3];
      }
    }
    float bo=ob[o];
    #pragma unroll
    for(int i=0;i<PTILE;i++){
      float a=acc[i]+bo;
      a = a>0.f ? a : 0.01f*a;
      out[(size_t)(4095-(tp0+i))*H_DIM + o]=a;
    }
  }
}

extern "C" void kernel_launch(void* const* d_in, const int* in_sizes, int n_in,
                              void* d_out, int out_size, void* d_ws, size_t ws_size,
                              hipStream_t stream) {
  const float* x    = (const float*)d_in[0];
  const float* eWih = (const float*)d_in[1];
  const float* eWhh = (const float*)d_in[2];
  const float* ebih = (const float*)d_in[3];
  const float* ebhh = (const float*)d_in[4];
  const float* dWih = (const float*)d_in[5];
  const float* dWhh = (const float*)d_in[6];
  const float* dbih = (const float*)d_in[7];
  const float* dbhh = (const float*)d_in[8];
  const float* oW   = (const float*)d_in[9];
  const float* ob   = (const float*)d_in[10];
  float* out = (float*)d_out;
  u32* ws = (u32*)d_ws;

  const size_t REGION = (size_t)NSLOT*SLOT_DW;     // in dwords
  u64*   SA    = (u64*)ws;
  u64*   SB    = (u64*)(ws + REGION);
  float* CA    = (float*)(ws + 2*REGION);          // 2048 floats: enc c finals
  u32*   panic = ws + 2*REGION + 2048;
  const size_t LSTRIDE = (size_t)4096*1024;        // per-layer weight stride

  // clear tags + c buffer + panic (stale same-magic tags from the previous
  // graph iteration must never false-positive)
  size_t clr_bytes = (2*REGION + 2048 + 64)*4;
  hipMemsetAsync(d_ws, 0, clr_bytes, stream);

  // Phase 1: enc L0 (mode 0, x -> SA/M1, zero init) || enc L1 (mode 1,
  // SA/M1 -> SB/M1, zero init, writes final_hidden to out tail).
  lstm_scan_pair<<<256,512,0,stream>>>(
      x, nullptr, SA, 0u, M1,
      eWih, eWhh, ebih, ebhh,
      nullptr, CA, nullptr, nullptr, 0,
      SA, SB, M1, M1,
      eWih+LSTRIDE, eWhh+LSTRIDE, ebih+4096, ebhh+4096,
      nullptr, CA+1024, nullptr, out + (size_t)T_STEPS*H_DIM, 1,
      panic);

  // Phase 2: dec L0 (mode 2, const input = final_hidden = SB slot 4096,
  // stream SA reused with M2, init h=SA slot 4096 / c=CA) || dec L1
  // (mode 3, SA/M2 -> SB/M2, init h=SB slot 4096 / c=CA+1024).
  lstm_scan_pair<<<256,512,0,stream>>>(
      nullptr, SB + (size_t)4096*SLOT_U64, SA, 0u, M2,
      dWih, dWhh, dbih, dbhh,
      CA, CA, SA + (size_t)4096*SLOT_U64, nullptr, 2,
      SA, SB, M2, M2,
      dWih+LSTRIDE, dWhh+LSTRIDE, dbih+4096, dbhh+4096,
      CA+1024, CA+1024, SB + (size_t)4096*SLOT_U64, nullptr, 3,
      panic);

  // projection + leaky ReLU + flip
  proj_out<<<256,256,0,stream>>>(SB, oW, ob, out);
}

// Round 6
// 23004.776 us; speedup vs baseline: 1.9753x; 1.6787x over previous
//
#include <hip/hip_runtime.h>
#include <stdint.h>

// ---------------------------------------------------------------------------
// Seq2seq LSTM autoencoder (T=4096, H=1024, L=2), fp32 end-to-end.
// Round 9: round-6 exchange protocol restored + round-8's good parts.
//   Round-8 post-mortem: scattered per-wave publish (8 partial-line writes
//   to one 64B line from 8 waves) quadrupled WRITE_SIZE (65->262 MB) and
//   regressed per-step 2.89->4.7us. Publish must be ONE coalesced store
//   from adjacent lanes of ONE wave (round 6). Sleep-free spin was also
//   reverted (all waves poll in-phase; s_sleep(4) steals nothing).
//   Kept from round 8 (independently good, both verified passing):
//   - wave-per-row compute: wave w owns h-row r (all 4 gates), in-wave
//     shfl reduce, lane 0 does gate math. No gl[] 32-float cross-wave
//     exchange, no tid<8 serialized gate math. h hops to wave 0 via an
//     8-float LDS array gh[] for the coalesced publish.
//   - tiled proj_out: 256 blocks x 16 timesteps, out_W traffic 16GB->1GB.
// Exchange (round-6 proven): tagged u64 per element
// ((MAGIC<<16|lo16),(MAGIC<<16|hi16)), agent-scope relaxed atomics, data IS
// the readiness signal (single LLC hop); publish = 8 adjacent lanes of
// wave 0 -> one 64B transaction; poll paced by s_sleep(4).
// Geometry: 128 blocks x 512 thr per layer (8 rows/block), pair = 256
// blocks -> 1 block/CU (launch_bounds(512,2), 128 weight floats in VGPRs).
// Per step: poll->fill st -> bar -> dot+reduce -> gates (lane0), gh[w]=h
// -> bar -> wave0 coalesced publish. Single LDS stage buffer is safe with
// 2 barriers (all dot reads complete before next fill).
// Schedule: pair(enc L0, enc L1) -> pair(dec L0, dec L1) -> proj.
// Deadlock-free: layer-A never waits on layer-B.
// ---------------------------------------------------------------------------

#define T_STEPS 4096
#define H_DIM   1024
#define SLOT_U64 1024             // 1024 elements x (2 tagged dwords = 1 u64)
#define SLOT_DW  2048
#define NSLOT   4097
#define M1 0x7E57u
#define M2 0x7E58u
#define PANIC_ITERS (1u<<25)

using u32 = uint32_t;
using u64 = unsigned long long;

static __device__ __forceinline__ float sigf(float x){ return 1.0f/(1.0f+__expf(-x)); }
static __device__ __forceinline__ float tanh_f(float x){
  x = fminf(20.f, fmaxf(-20.f, x));
  float e = __expf(-2.f*x);
  return (1.f-e)/(1.f+e);
}

static __device__ __forceinline__ bool tag_ok(u64 v, u32 magic){
  return ((((u32)(v>>16))&0xFFFFu)==magic) & (((u32)(v>>48))==magic);
}
static __device__ __forceinline__ float untag1(u64 v){
  return __uint_as_float( (((u32)v)&0xFFFFu) | (((u32)(v>>32))<<16) );
}
static __device__ __forceinline__ u64 tag1(u32 magic, float h){
  u32 b=__float_as_uint(h);
  u64 lo = (u64)((magic<<16)|(b&0xFFFFu));
  u64 hi = ((u64)((magic<<16)|(b>>16)))<<32;
  return hi|lo;
}

// Poll 2 tagged elements (one u64 each) until valid; deposit into LDS.
// s_sleep(4)-paced (round-6 proven); panic escape for true deadlocks.
static __device__ __forceinline__ void poll_h2(const u64* __restrict__ q,
                                               u32 magic, float* dst,
                                               u32* panic){
  u64 v0=0,v1=0; bool ok0=false,ok1=false; u32 it=0;
  for(;;){
    if(!ok0) v0=__hip_atomic_load(q,  __ATOMIC_RELAXED,__HIP_MEMORY_SCOPE_AGENT);
    if(!ok1) v1=__hip_atomic_load(q+1,__ATOMIC_RELAXED,__HIP_MEMORY_SCOPE_AGENT);
    ok0 = ok0 || tag_ok(v0,magic);
    ok1 = ok1 || tag_ok(v1,magic);
    if(ok0 & ok1) break;
    ++it;
    if((it & 255u)==0u){
      if(__hip_atomic_load(panic,__ATOMIC_RELAXED,__HIP_MEMORY_SCOPE_AGENT)==0xDEADBEEFu) break;
      if(it>PANIC_ITERS){ __hip_atomic_store(panic,0xDEADBEEFu,__ATOMIC_RELAXED,__HIP_MEMORY_SCOPE_AGENT); break; }
    }
    __builtin_amdgcn_s_sleep(4);
  }
  dst[0]=untag1(v0);
  dst[1]=untag1(v1);
}

// Poll 2 IN + 2 H tagged elements concurrently (modes 1/3).
static __device__ __forceinline__ void poll_in2h2(const u64* __restrict__ qa, u32 mA,
                                                  const u64* __restrict__ qb, u32 mB,
                                                  float* da, float* db, u32* panic){
  u64 a0=0,a1=0,b0=0,b1=0; bool oa0=false,oa1=false,ob0=false,ob1=false; u32 it=0;
  for(;;){
    if(!oa0) a0=__hip_atomic_load(qa,  __ATOMIC_RELAXED,__HIP_MEMORY_SCOPE_AGENT);
    if(!oa1) a1=__hip_atomic_load(qa+1,__ATOMIC_RELAXED,__HIP_MEMORY_SCOPE_AGENT);
    if(!ob0) b0=__hip_atomic_load(qb,  __ATOMIC_RELAXED,__HIP_MEMORY_SCOPE_AGENT);
    if(!ob1) b1=__hip_atomic_load(qb+1,__ATOMIC_RELAXED,__HIP_MEMORY_SCOPE_AGENT);
    oa0 = oa0 || tag_ok(a0,mA);
    oa1 = oa1 || tag_ok(a1,mA);
    ob0 = ob0 || tag_ok(b0,mB);
    ob1 = ob1 || tag_ok(b1,mB);
    if(oa0 & oa1 & ob0 & ob1) break;
    ++it;
    if((it & 255u)==0u){
      if(__hip_atomic_load(panic,__ATOMIC_RELAXED,__HIP_MEMORY_SCOPE_AGENT)==0xDEADBEEFu) break;
      if(it>PANIC_ITERS){ __hip_atomic_store(panic,0xDEADBEEFu,__ATOMIC_RELAXED,__HIP_MEMORY_SCOPE_AGENT); break; }
    }
    __builtin_amdgcn_s_sleep(4);
  }
  da[0]=untag1(a0); da[1]=untag1(a1);
  db[0]=untag1(b0); db[1]=untag1(b1);
}

// One LSTM layer over T steps. kb = block index within the layer (0..127).
// Block owns h-rows hr0..hr0+7; wave w owns row r=hr0+w entirely (4 gates).
// Lane l = one 32-col segment (lanes 0-31 input part, 32-63 h part).
// Thread stages stream elements 2*tid, 2*tid+1 of both IN and H parts.
// mode 0: input = raw x.  mode 1/3: input = tagged stream (m_in).
// mode 2: input = CONSTANT tagged slot (staged once; in-part never touched
// again since mode-2 blocks only refill the H region each step).
static __device__ __forceinline__ void lstm_scan_body(
    int kb, int tid, float* st, float* gh,
    const float* __restrict__ xin,
    const u64*  __restrict__ instream,
    u64*        __restrict__ own,
    u32 m_in, u32 m_own,
    const float* __restrict__ Wih, const float* __restrict__ Whh,
    const float* __restrict__ bih, const float* __restrict__ bhh,
    const float* __restrict__ c0,      // null -> zeros
    float*       __restrict__ cout,    // final c per row
    const u64*  __restrict__ h0slot,   // tagged slot holding h0; null -> zeros
    float*       __restrict__ fh_out,  // if non-null: write final h (enc L1)
    u32* __restrict__ panic,
    int mode)
{
  const int hr0=kb*8;
  const int w=tid>>6, l=tid&63;
  const int r = hr0 + w;                   // this wave's h row
  const int e0 = 2*tid;                    // first owned stream element
  const int fb  = e0 + 4*(e0>>5);          // stage word, IN part (2 elems)
  const int fbH = 1152+fb;                 // stage word, H part
  const int sb  = l*36;                    // dot segment word base

  // fp32 weights in registers: 4 gate rows (i,f,g,o) x 32-col segment
  float wr0[32],wr1[32],wr2[32],wr3[32];
  {
    const size_t GS = (size_t)1024*1024;   // gate stride in floats
    const float* srcb = (l<32) ? Wih + (size_t)r*H_DIM + l*32
                               : Whh + (size_t)r*H_DIM + (l-32)*32;
    #pragma unroll
    for(int i=0;i<8;i++){
      float4 a0=*(const float4*)(srcb + i*4);
      float4 a1=*(const float4*)(srcb + GS + i*4);
      float4 a2=*(const float4*)(srcb + 2*GS + i*4);
      float4 a3=*(const float4*)(srcb + 3*GS + i*4);
      wr0[4*i]=a0.x; wr0[4*i+1]=a0.y; wr0[4*i+2]=a0.z; wr0[4*i+3]=a0.w;
      wr1[4*i]=a1.x; wr1[4*i+1]=a1.y; wr1[4*i+2]=a1.z; wr1[4*i+3]=a1.w;
      wr2[4*i]=a2.x; wr2[4*i+1]=a2.y; wr2[4*i+2]=a2.z; wr2[4*i+3]=a2.w;
      wr3[4*i]=a3.x; wr3[4*i+1]=a3.y; wr3[4*i+2]=a3.z; wr3[4*i+3]=a3.w;
    }
  }

  float bI=0,bF=0,bG=0,bO=0,c_st=0.f,h_st=0.f;   // valid on lane 0 of each wave
  if(l==0){
    bI=bih[r]       + bhh[r];
    bF=bih[r+1024]  + bhh[r+1024];
    bG=bih[r+2048]  + bhh[r+2048];
    bO=bih[r+3072]  + bhh[r+3072];
    if(c0)     c_st=c0[r];
    if(h0slot) h_st=untag1(h0slot[r]);
    gh[w]=h_st;
  }
  if(mode==2){                 // constant input: stage once (region persists)
    st[fb]  =untag1(instream[e0]);
    st[fb+1]=untag1(instream[e0+1]);
  }
  __syncthreads();
  // publish slot 0 (h0): 8 adjacent lanes of wave 0 -> one 64B transaction
  if(tid<8){
    __hip_atomic_store(own + hr0 + tid, tag1(m_own, gh[tid]),
                       __ATOMIC_RELAXED,__HIP_MEMORY_SCOPE_AGENT);
  }

  for(int t=0;t<T_STEPS;++t){
    // --- fill stage buffer (poll = single-hop tagged exchange) ---
    if(mode==0){
      float2 xv=*(const float2*)(xin + (size_t)t*H_DIM + e0);  // issue early
      poll_h2(own + (size_t)t*SLOT_U64 + e0, m_own, st+fbH, panic);
      st[fb]=xv.x; st[fb+1]=xv.y;                              // lands in poll
    } else if(mode==2){
      poll_h2(own + (size_t)t*SLOT_U64 + e0, m_own, st+fbH, panic);
    } else {
      poll_in2h2(instream + (size_t)(t+1)*SLOT_U64 + e0, m_in,
                 own      + (size_t)t*SLOT_U64     + e0, m_own,
                 st+fb, st+fbH, panic);
    }
    __syncthreads();
    // --- dot: 4 gates of row r over this lane's 32-col segment ---
    float p0=0.f,p1=0.f,p2=0.f,p3=0.f;
    #pragma unroll
    for(int i=0;i<8;i++){
      float4 s=*(const float4*)(st+sb+i*4);
      p0+=s.x*wr0[4*i]+s.y*wr0[4*i+1]+s.z*wr0[4*i+2]+s.w*wr0[4*i+3];
      p1+=s.x*wr1[4*i]+s.y*wr1[4*i+1]+s.z*wr1[4*i+2]+s.w*wr1[4*i+3];
      p2+=s.x*wr2[4*i]+s.y*wr2[4*i+1]+s.z*wr2[4*i+2]+s.w*wr2[4*i+3];
      p3+=s.x*wr3[4*i]+s.y*wr3[4*i+1]+s.z*wr3[4*i+2]+s.w*wr3[4*i+3];
    }
    #pragma unroll
    for(int off=32;off;off>>=1){
      p0+=__shfl_down(p0,off,64); p1+=__shfl_down(p1,off,64);
      p2+=__shfl_down(p2,off,64); p3+=__shfl_down(p3,off,64);
    }
    // --- gates fully in-wave (lane 0); h hops to wave 0 via gh[] ---
    if(l==0){
      float gi=bI+p0, gf=bF+p1, gg=bG+p2, go=bO+p3;
      c_st = sigf(gf)*c_st + sigf(gi)*tanh_f(gg);
      h_st = sigf(go)*tanh_f(c_st);
      gh[w]=h_st;
      if(t==T_STEPS-1){
        cout[r]=c_st;
        if(fh_out) fh_out[r]=h_st;
      }
    }
    __syncthreads();
    // --- coalesced publish: 8 adjacent lanes of wave 0, one 64B line ---
    if(tid<8){
      __hip_atomic_store(own + (size_t)(t+1)*SLOT_U64 + hr0 + tid,
                         tag1(m_own, gh[tid]),
                         __ATOMIC_RELAXED,__HIP_MEMORY_SCOPE_AGENT);
    }
    // single stage buffer is safe: all dot reads of st completed before
    // this barrier; next fill starts only after it.
  }
}

// Fused layer pair: blocks [0,128) = layer A, [128,256) = layer B.
// B consumes A's stream with 1-step skew. A never waits on B.
__global__ __launch_bounds__(512,2) void lstm_scan_pair(
    const float* __restrict__ xinA,
    const u64*  __restrict__ insA, u64* __restrict__ ownA, u32 miA, u32 moA,
    const float* __restrict__ WihA, const float* __restrict__ WhhA,
    const float* __restrict__ bihA, const float* __restrict__ bhhA,
    const float* __restrict__ c0A, float* __restrict__ coutA,
    const u64*  __restrict__ h0A, float* __restrict__ fhA, int modeA,
    const u64*  __restrict__ insB, u64* __restrict__ ownB, u32 miB, u32 moB,
    const float* __restrict__ WihB, const float* __restrict__ WhhB,
    const float* __restrict__ bihB, const float* __restrict__ bhhB,
    const float* __restrict__ c0B, float* __restrict__ coutB,
    const u64*  __restrict__ h0B, float* __restrict__ fhB, int modeB,
    u32* __restrict__ panic)
{
  __shared__ __align__(16) float st[2304];
  __shared__ float gh[8];
  const int b=blockIdx.x, tid=threadIdx.x;
  if(b<128){
    lstm_scan_body(b, tid, st, gh, xinA, insA, ownA, miA, moA,
                   WihA, WhhA, bihA, bhhA, c0A, coutA, h0A, fhA, panic, modeA);
  } else {
    lstm_scan_body(b-128, tid, st, gh, nullptr, insB, ownB, miB, moB,
                   WihB, WhhB, bihB, bhhB, c0B, coutB, h0B, fhB, panic, modeB);
  }
}

// out[(4095-tp), o] = leaky( sum_k oW[o,k] * h1d[tp][k] + ob[o] )
// Tiled: each block handles PTILE timesteps, staging h in LDS, so out_W is
// read 256x total (1 GB LLC traffic) instead of 4096x (16 GB).
#define PTILE 16
__global__ __launch_bounds__(256,2) void proj_out(
    const u64* __restrict__ SB, const float* __restrict__ oW,
    const float* __restrict__ ob, float* __restrict__ out)
{
  __shared__ __align__(16) float hb[PTILE][1024];
  const int tp0=blockIdx.x*PTILE, tid=threadIdx.x;
  for(int i=0;i<PTILE;i++){
    u64 v0=SB[(size_t)(tp0+i+1)*SLOT_U64 + tid*4 + 0];
    u64 v1=SB[(size_t)(tp0+i+1)*SLOT_U64 + tid*4 + 1];
    u64 v2=SB[(size_t)(tp0+i+1)*SLOT_U64 + tid*4 + 2];
    u64 v3=SB[(size_t)(tp0+i+1)*SLOT_U64 + tid*4 + 3];
    float4 f; f.x=untag1(v0); f.y=untag1(v1); f.z=untag1(v2); f.w=untag1(v3);
    *(float4*)&hb[i][tid*4]=f;
  }
  __syncthreads();
  #pragma unroll
  for(int j=0;j<4;j++){
    int o = tid + 256*j;
    const float* wr = oW + (size_t)o*H_DIM;
    float acc[PTILE];
    #pragma unroll
    for(int i=0;i<PTILE;i++) acc[i]=0.f;
    for(int k=0;k<1024;k+=4){
      float4 wv=*(const float4*)(wr+k);
      #pragma unroll
      for(int i=0;i<PTILE;i++){
        acc[i] += wv.x*hb[i][k]+wv.y*hb[i][k+1]+wv.z*hb[i][k+2]+wv.w*hb[i][k+3];
      }
    }
    float bo=ob[o];
    #pragma unroll
    for(int i=0;i<PTILE;i++){
      float a=acc[i]+bo;
      a = a>0.f ? a : 0.01f*a;
      out[(size_t)(4095-(tp0+i))*H_DIM + o]=a;
    }
  }
}

extern "C" void kernel_launch(void* const* d_in, const int* in_sizes, int n_in,
                              void* d_out, int out_size, void* d_ws, size_t ws_size,
                              hipStream_t stream) {
  const float* x    = (const float*)d_in[0];
  const float* eWih = (const float*)d_in[1];
  const float* eWhh = (const float*)d_in[2];
  const float* ebih = (const float*)d_in[3];
  const float* ebhh = (const float*)d_in[4];
  const float* dWih = (const float*)d_in[5];
  const float* dWhh = (const float*)d_in[6];
  const float* dbih = (const float*)d_in[7];
  const float* dbhh = (const float*)d_in[8];
  const float* oW   = (const float*)d_in[9];
  const float* ob   = (const float*)d_in[10];
  float* out = (float*)d_out;
  u32* ws = (u32*)d_ws;

  const size_t REGION = (size_t)NSLOT*SLOT_DW;     // in dwords
  u64*   SA    = (u64*)ws;
  u64*   SB    = (u64*)(ws + REGION);
  float* CA    = (float*)(ws + 2*REGION);          // 2048 floats: enc c finals
  u32*   panic = ws + 2*REGION + 2048;
  const size_t LSTRIDE = (size_t)4096*1024;        // per-layer weight stride

  // clear tags + c buffer + panic (stale same-magic tags from the previous
  // graph iteration must never false-positive)
  size_t clr_bytes = (2*REGION + 2048 + 64)*4;
  hipMemsetAsync(d_ws, 0, clr_bytes, stream);

  // Phase 1: enc L0 (mode 0, x -> SA/M1, zero init) || enc L1 (mode 1,
  // SA/M1 -> SB/M1, zero init, writes final_hidden to out tail).
  lstm_scan_pair<<<256,512,0,stream>>>(
      x, nullptr, SA, 0u, M1,
      eWih, eWhh, ebih, ebhh,
      nullptr, CA, nullptr, nullptr, 0,
      SA, SB, M1, M1,
      eWih+LSTRIDE, eWhh+LSTRIDE, ebih+4096, ebhh+4096,
      nullptr, CA+1024, nullptr, out + (size_t)T_STEPS*H_DIM, 1,
      panic);

  // Phase 2: dec L0 (mode 2, const input = final_hidden = SB slot 4096,
  // stream SA reused with M2, init h=SA slot 4096 / c=CA) || dec L1
  // (mode 3, SA/M2 -> SB/M2, init h=SB slot 4096 / c=CA+1024).
  lstm_scan_pair<<<256,512,0,stream>>>(
      nullptr, SB + (size_t)4096*SLOT_U64, SA, 0u, M2,
      dWih, dWhh, dbih, dbhh,
      CA, CA, SA + (size_t)4096*SLOT_U64, nullptr, 2,
      SA, SB, M2, M2,
      dWih+LSTRIDE, dWhh+LSTRIDE, dbih+4096, dbhh+4096,
      CA+1024, CA+1024, SB + (size_t)4096*SLOT_U64, nullptr, 3,
      panic);

  // projection + leaky ReLU + flip
  proj_out<<<256,256,0,stream>>>(SB, oW, ob, out);
}